// Round 9
// baseline (783.313 us; speedup 1.0000x reference)
//
#include <hip/hip_runtime.h>
#include <math.h>

// ---------------- problem constants ----------------
constexpr int Bc = 2, Cc = 64, Nc = 50000, Kc = 8;
constexpr int PT = 16;                       // points per wave (MFMA M dim)
constexpr int WPB = 4;                       // waves per block
constexpr int NTILE = (Bc * Nc) / PT;        // 6250 wave-tiles
constexpr int NBLK = (NTILE + WPB - 1) / WPB;  // 1563 (tail waves clamp+duplicate)

// ---------------- ws byte layout ----------------
constexpr int BIAS_PH = 16;                  // f32[64]
constexpr int BIAS_N1 = 272;                 // f32[64]
constexpr int BIAS_DL = 528;                 // f32[32] (sv folded, padded)
constexpr int B_PH  = 1024;                  // 12 frags * 1KB
constexpr int B_N1  = 13312;                 // 12 frags
constexpr int B_DH  = 25600;                 // 6 frags (delta hi)
constexpr int B_DLO = 31744;                 // 6 frags (delta lo)
constexpr int B_N2  = 37888;                 // 72 frags -> ends 111616
constexpr size_t XT_BYTE = 262144;           // bf16 volume starts here
constexpr size_t XT_USHORTS = (size_t)Bc * 64 * 64 * 64 * 64;

using bf16x8 = __attribute__((ext_vector_type(8))) short;
using f32x4  = __attribute__((ext_vector_type(4))) float;

// ---------------- helpers ----------------
__device__ __forceinline__ float gelu_exact(float v) {
    return 0.5f * v * (1.0f + erff(v * 0.70710678118654752f));
}
__device__ __forceinline__ ushort f2bf(float f) {           // RNE f32 -> bf16 bits
    unsigned u = __float_as_uint(f);
    unsigned r = (u + 0x7FFFu + ((u >> 16) & 1u)) >> 16;
    return (ushort)r;
}
__device__ __forceinline__ float bf2f(ushort u) {
    return __uint_as_float(((unsigned)u) << 16);
}

// ---- transposed channel-minor bf16 sampling: 1 cache line per corner ----
__device__ __forceinline__ float sample_tr(const ushort* __restrict__ xtb, int lane,
                                           float gx, float gy, float gz) {
    float ix = fminf(fmaxf((gx + 1.0f) * 31.5f, 0.0f), 63.0f);
    float iy = fminf(fmaxf((gy + 1.0f) * 31.5f, 0.0f), 63.0f);
    float iz = fminf(fmaxf((gz + 1.0f) * 31.5f, 0.0f), 63.0f);
    float fx0 = floorf(ix), fy0 = floorf(iy), fz0 = floorf(iz);
    int x0 = (int)fx0, y0 = (int)fy0, z0 = (int)fz0;
    float fx = ix - fx0, fy = iy - fy0, fz = iz - fz0;
    int dx = (x0 < 63) ? 64 : 0;
    int dy = (y0 < 63) ? 4096 : 0;
    int dz = (z0 < 63) ? 262144 : 0;
    const ushort* r = xtb + ((((z0 << 12) + (y0 << 6) + x0) << 6) + lane);
    float v000 = bf2f(r[0]),       v001 = bf2f(r[dx]);
    float v010 = bf2f(r[dy]),      v011 = bf2f(r[dy + dx]);
    float v100 = bf2f(r[dz]),      v101 = bf2f(r[dz + dx]);
    float v110 = bf2f(r[dz + dy]), v111 = bf2f(r[dz + dy + dx]);
    float c00 = fmaf(fx, v001 - v000, v000);
    float c01 = fmaf(fx, v011 - v010, v010);
    float c10 = fmaf(fx, v101 - v100, v100);
    float c11 = fmaf(fx, v111 - v110, v110);
    float c0  = fmaf(fy, c01 - c00, c00);
    float c1  = fmaf(fy, c11 - c10, c10);
    return fmaf(fz, c1 - c0, c0);
}

// ---- fallback (channel-major f32) sampling ----
__device__ __forceinline__ float sample_cm(const float* __restrict__ xb,
                                           float gx, float gy, float gz) {
    float ix = fminf(fmaxf((gx + 1.0f) * 31.5f, 0.0f), 63.0f);
    float iy = fminf(fmaxf((gy + 1.0f) * 31.5f, 0.0f), 63.0f);
    float iz = fminf(fmaxf((gz + 1.0f) * 31.5f, 0.0f), 63.0f);
    float fx0 = floorf(ix), fy0 = floorf(iy), fz0 = floorf(iz);
    int x0 = (int)fx0, y0 = (int)fy0, z0 = (int)fz0;
    float fx = ix - fx0, fy = iy - fy0, fz = iz - fz0;
    int x1 = (x0 < 63) ? x0 + 1 : 63;
    int dy = (y0 < 63) ? 64 : 0;
    int dz = (z0 < 63) ? 4096 : 0;
    const float* r = xb + ((z0 << 12) + (y0 << 6));
    float v000 = r[x0],           v001 = r[x1];
    float v010 = r[x0 + dy],      v011 = r[x1 + dy];
    float v100 = r[x0 + dz],      v101 = r[x1 + dz];
    float v110 = r[x0 + dy + dz], v111 = r[x1 + dy + dz];
    float c00 = fmaf(fx, v001 - v000, v000);
    float c01 = fmaf(fx, v011 - v010, v010);
    float c10 = fmaf(fx, v101 - v100, v100);
    float c11 = fmaf(fx, v111 - v110, v110);
    float c0  = fmaf(fy, c01 - c00, c00);
    float c1  = fmaf(fy, c11 - c10, c10);
    return fmaf(fz, c1 - c0, c0);
}

// ---------------- weight packing: B-fragment lane order, bf16 ----------------
__global__ void sb_pack(const float* __restrict__ shape_w, const float* __restrict__ shape_b,
                        const float* __restrict__ delta_w, const float* __restrict__ delta_b,
                        const float* __restrict__ ph_w, const float* __restrict__ ph_b,
                        const float* __restrict__ nh1_w, const float* __restrict__ nh1_b,
                        const float* __restrict__ nh2_w, char* __restrict__ wsb) {
    int tid = blockIdx.x * blockDim.x + threadIdx.x;
    int nt  = gridDim.x * blockDim.x;
    float*  bph = (float*)(wsb + BIAS_PH);
    float*  bn1 = (float*)(wsb + BIAS_N1);
    float*  bdl = (float*)(wsb + BIAS_DL);
    ushort* wph = (ushort*)(wsb + B_PH);
    ushort* wn1 = (ushort*)(wsb + B_N1);
    ushort* wdh = (ushort*)(wsb + B_DH);
    ushort* wdl = (ushort*)(wsb + B_DLO);
    ushort* wn2 = (ushort*)(wsb + B_N2);

    for (int e = tid; e < 64; e += nt) { bph[e] = ph_b[e]; bn1[e] = nh1_b[e]; }
    for (int e = tid; e < 32; e += nt) {
        float v = 0.0f;
        if (e < 24) {
            v = delta_b[e];
#pragma unroll
            for (int i = 0; i < 4; ++i) {   // fold shape_vec (constant) into bias, f32 exact
                float sv = 64.0f * (shape_w[i*4] + shape_w[i*4+1] + shape_w[i*4+2] + shape_w[i*4+3])
                         + shape_b[i];
                v += sv * delta_w[e * 71 + 67 + i];
            }
        }
        bdl[e] = v;
    }
    // ph / nh1: 12 frags each; frag = kt*4+n; B[k][col], lane l: k=(kt*32+(l>>4)*8+j), col=n*16+(l&15)
    for (int e = tid; e < 6144; e += nt) {
        int frag = e >> 9, lane = (e >> 3) & 63, j = e & 7;
        int kt = frag >> 2, n = frag & 3;
        int k = kt * 32 + ((lane >> 4) << 3) + j;
        int col = n * 16 + (lane & 15);
        wph[e] = (k < 67) ? f2bf(ph_w[col * 67 + k])  : (ushort)0;
        wn1[e] = (k < 67) ? f2bf(nh1_w[col * 67 + k]) : (ushort)0;
    }
    // delta hi/lo: 6 frags; frag = kt*2+n (n-tiles cols 0..31, real 0..23)
    for (int e = tid; e < 3072; e += nt) {
        int frag = e >> 9, lane = (e >> 3) & 63, j = e & 7;
        int kt = frag >> 1, n = frag & 1;
        int k = kt * 32 + ((lane >> 4) << 3) + j;
        int col = n * 16 + (lane & 15);
        float w = (col < 24 && k < 67) ? delta_w[col * 71 + k] : 0.0f;
        ushort hi = f2bf(w);
        wdh[e] = hi;
        wdl[e] = f2bf(w - bf2f(hi));
    }
    // nh2: 72 frags; frag = c9*8 + kt*4 + n ; B[k=c'][col=c] = nh2_w[c][c'][c9]
    for (int e = tid; e < 36864; e += nt) {
        int frag = e >> 9, lane = (e >> 3) & 63, j = e & 7;
        int c9 = frag >> 3, kt = (frag >> 2) & 1, n = frag & 3;
        int k = kt * 32 + ((lane >> 4) << 3) + j;
        int c = n * 16 + (lane & 15);
        wn2[e] = f2bf(nh2_w[(c * 64 + k) * 9 + c9]);
    }
}

// ---------------- transpose x [B,C,64^3] f32 -> xt [B,64^3,C] bf16 ----------------
__global__ __launch_bounds__(256) void sb_transpose(const float* __restrict__ x,
                                                    ushort* __restrict__ xt) {
    __shared__ float tile[64][65];
    int blk = blockIdx.x;
    int b = blk >> 12, zy = blk & 4095;
    const float* __restrict__ src = x + ((size_t)b << 24) + zy * 64;
    unsigned* __restrict__ dst32 = (unsigned*)(xt + ((size_t)b << 24) + (size_t)zy * 4096);
    int t = threadIdx.x;
    int xx = t & 63, c0 = t >> 6;
#pragma unroll
    for (int i = 0; i < 16; ++i) {
        int c = i * 4 + c0;
        tile[c][xx] = src[((size_t)c << 18) + xx];
    }
    __syncthreads();
    int cp = t & 31, xs0 = t >> 5;
#pragma unroll
    for (int i = 0; i < 8; ++i) {
        int xs = i * 8 + xs0;
        unsigned lo = f2bf(tile[cp * 2][xs]);
        unsigned hi = f2bf(tile[cp * 2 + 1][xs]);
        dst32[xs * 32 + cp] = lo | (hi << 16);
    }
}

// ---------------- main MFMA kernel: 4 waves/block, 1 wave = 16 points ----------------
__global__ __launch_bounds__(64 * WPB) void sb_main_mfma(
        const ushort* __restrict__ xt, const float* __restrict__ verts,
        const char* __restrict__ wsb, float* __restrict__ out) {
    // per-wave private LDS slices (no cross-wave sharing)
    __shared__ __align__(16) ushort stage_s[WPB][PT * 104];  // A tile [point][K..95]
    __shared__ __align__(16) ushort hst_s[WPB][PT * 72];     // gelu(h) A tile
    __shared__ float cst_s[WPB][PT * 4];                     // vertex coords
    __shared__ float dls_s[WPB][PT * 32];                    // delta outputs

    const int tid  = threadIdx.x;
    const int wid  = tid >> 6, lane = tid & 63;
    const int l15  = lane & 15, lg = lane >> 4;
    int tile = blockIdx.x * WPB + wid;
    if (tile >= NTILE) tile = NTILE - 1;        // tail waves duplicate last tile (benign)
    const int g0 = tile * PT;
    const ushort* __restrict__ xtb = xt + ((size_t)(g0 / Nc) << 24);

    ushort* stage = stage_s[wid];
    ushort* hst   = hst_s[wid];
    float*  cst   = cst_s[wid];
    float*  dls   = dls_s[wid];

    const float*  bph = (const float*)(wsb + BIAS_PH);
    const float*  bn1 = (const float*)(wsb + BIAS_N1);
    const float*  bdl = (const float*)(wsb + BIAS_DL);
    const ushort* Wph = (const ushort*)(wsb + B_PH);
    const ushort* Wn1 = (const ushort*)(wsb + B_N1);
    const ushort* Wdh = (const ushort*)(wsb + B_DH);
    const ushort* Wdl = (const ushort*)(wsb + B_DLO);
    const ushort* Wn2 = (const ushort*)(wsb + B_N2);

    // ---- zero-init A tile (pad cols 72..103 read by MFMA vs zero weights;
    // uninitialized LDS can hold NaN bits and NaN*0=NaN in the dot product).
#pragma unroll
    for (int i = 0; i < (PT * 104) / 64; ++i) stage[i * 64 + lane] = 0;

    float bias_p[4], bias_h[4], bias_d[2];
#pragma unroll
    for (int n = 0; n < 4; ++n) { bias_p[n] = bph[n*16 + l15]; bias_h[n] = bn1[n*16 + l15]; }
#pragma unroll
    for (int n = 0; n < 2; ++n) bias_d[n] = bdl[n*16 + l15];

    // init: verts -> cst + stage coord block (cols 64..71; 67.. zero, weights zero-padded)
    if (lane < PT) {
        const float* vp = verts + (size_t)(g0 + lane) * 3;
        float x = vp[0], y = vp[1], z = vp[2];
        cst[lane*4+0] = x; cst[lane*4+1] = y; cst[lane*4+2] = z;
        uint4 cw;
        cw.x = (unsigned)f2bf(x) | ((unsigned)f2bf(y) << 16);
        cw.y = (unsigned)f2bf(z);
        cw.z = 0u; cw.w = 0u;
        *(uint4*)(stage + lane * 104 + 64) = cw;
    }
    __syncthreads();

    // ---- sample column 0 (lane = channel; coords from cst broadcast) ----
#pragma unroll 4
    for (int p = 0; p < PT; ++p) {
        float s = sample_tr(xtb, lane, cst[p*4], cst[p*4+1], cst[p*4+2]);
        stage[p * 104 + lane] = f2bf(s);
    }
    __syncthreads();

    // ---- merged GEMM pass: ph + nh1(col0) + delta(hi+lo), K=96 (3 ksteps) ----
    f32x4 pf[4], nf[4], hh[4], dd[2];
#pragma unroll
    for (int n = 0; n < 4; ++n) {
        pf[n] = (f32x4){bias_p[n], bias_p[n], bias_p[n], bias_p[n]};
        hh[n] = (f32x4){bias_h[n], bias_h[n], bias_h[n], bias_h[n]};
        nf[n] = (f32x4){0.f, 0.f, 0.f, 0.f};
    }
#pragma unroll
    for (int n = 0; n < 2; ++n) dd[n] = (f32x4){bias_d[n], bias_d[n], bias_d[n], bias_d[n]};

    __builtin_amdgcn_s_setprio(1);
#pragma unroll
    for (int kt = 0; kt < 3; ++kt) {
        bf16x8 a = *(const bf16x8*)(stage + l15 * 104 + kt * 32 + lg * 8);
#pragma unroll
        for (int n = 0; n < 4; ++n) {
            bf16x8 bw = *(const bf16x8*)(Wph + ((kt*4 + n) << 9) + lane * 8);
            pf[n] = __builtin_amdgcn_mfma_f32_16x16x32_bf16(a, bw, pf[n], 0, 0, 0);
            bf16x8 b1 = *(const bf16x8*)(Wn1 + ((kt*4 + n) << 9) + lane * 8);
            hh[n] = __builtin_amdgcn_mfma_f32_16x16x32_bf16(a, b1, hh[n], 0, 0, 0);
        }
#pragma unroll
        for (int n = 0; n < 2; ++n) {
            bf16x8 bh = *(const bf16x8*)(Wdh + ((kt*2 + n) << 9) + lane * 8);
            dd[n] = __builtin_amdgcn_mfma_f32_16x16x32_bf16(a, bh, dd[n], 0, 0, 0);
            bf16x8 bl = *(const bf16x8*)(Wdl + ((kt*2 + n) << 9) + lane * 8);
            dd[n] = __builtin_amdgcn_mfma_f32_16x16x32_bf16(a, bl, dd[n], 0, 0, 0);
        }
    }
    __builtin_amdgcn_s_setprio(0);
    // D layout: row=(lg*4+r) [point], col=n*16+l15
#pragma unroll
    for (int n = 0; n < 2; ++n)
#pragma unroll
        for (int r = 0; r < 4; ++r)
            dls[(lg*4 + r) * 32 + n*16 + l15] = dd[n][r];
#pragma unroll
    for (int n = 0; n < 4; ++n)
#pragma unroll
        for (int r = 0; r < 4; ++r)
            hst[(lg*4 + r) * 72 + n*16 + l15] = f2bf(gelu_exact(hh[n][r]));
    __syncthreads();

    // ---- nh2 column 0 (K=64, 2 ksteps) ----
    __builtin_amdgcn_s_setprio(1);
#pragma unroll
    for (int kt = 0; kt < 2; ++kt) {
        bf16x8 a = *(const bf16x8*)(hst + l15 * 72 + kt * 32 + lg * 8);
#pragma unroll
        for (int n = 0; n < 4; ++n) {
            bf16x8 bw = *(const bf16x8*)(Wn2 + ((kt*4 + n) << 9) + lane * 8);
            nf[n] = __builtin_amdgcn_mfma_f32_16x16x32_bf16(a, bw, nf[n], 0, 0, 0);
        }
    }
    __builtin_amdgcn_s_setprio(0);

    // ---- neighbour columns 1..8 ----
    for (int k = 0; k < Kc; ++k) {
        // coord staging (lane p writes its row's coord block from cst+dls broadcast)
        if (lane < PT) {
            float x = cst[lane*4+0] + dls[lane*32 + 3*k + 0];
            float y = cst[lane*4+1] + dls[lane*32 + 3*k + 1];
            float z = cst[lane*4+2] + dls[lane*32 + 3*k + 2];
            uint4 cw;
            cw.x = (unsigned)f2bf(x) | ((unsigned)f2bf(y) << 16);
            cw.y = (unsigned)f2bf(z);
            cw.z = 0u; cw.w = 0u;
            *(uint4*)(stage + lane * 104 + 64) = cw;
        }
        // sampling: every lane recomputes coords from cst/dls (wave-uniform LDS broadcast)
#pragma unroll 4
        for (int p = 0; p < PT; ++p) {
            float nx = cst[p*4+0] + dls[p*32 + 3*k + 0];
            float ny = cst[p*4+1] + dls[p*32 + 3*k + 1];
            float nz = cst[p*4+2] + dls[p*32 + 3*k + 2];
            float s = sample_tr(xtb, lane, nx, ny, nz);
            stage[p * 104 + lane] = f2bf(s);
        }
        __syncthreads();

        f32x4 hk[4];
#pragma unroll
        for (int n = 0; n < 4; ++n) hk[n] = (f32x4){bias_h[n], bias_h[n], bias_h[n], bias_h[n]};
        __builtin_amdgcn_s_setprio(1);
#pragma unroll
        for (int kt = 0; kt < 3; ++kt) {
            bf16x8 a = *(const bf16x8*)(stage + l15 * 104 + kt * 32 + lg * 8);
#pragma unroll
            for (int n = 0; n < 4; ++n) {
                bf16x8 b1 = *(const bf16x8*)(Wn1 + ((kt*4 + n) << 9) + lane * 8);
                hk[n] = __builtin_amdgcn_mfma_f32_16x16x32_bf16(a, b1, hk[n], 0, 0, 0);
            }
        }
        __builtin_amdgcn_s_setprio(0);
#pragma unroll
        for (int n = 0; n < 4; ++n)
#pragma unroll
            for (int r = 0; r < 4; ++r)
                hst[(lg*4 + r) * 72 + n*16 + l15] = f2bf(gelu_exact(hk[n][r]));
        __syncthreads();

        const ushort* Wk = Wn2 + ((size_t)(k + 1) << 12);   // (k+1)*8 frags * 512
        __builtin_amdgcn_s_setprio(1);
#pragma unroll
        for (int kt = 0; kt < 2; ++kt) {
            bf16x8 a = *(const bf16x8*)(hst + l15 * 72 + kt * 32 + lg * 8);
#pragma unroll
            for (int n = 0; n < 4; ++n) {
                bf16x8 bw = *(const bf16x8*)(Wk + ((kt*4 + n) << 9) + lane * 8);
                nf[n] = __builtin_amdgcn_mfma_f32_16x16x32_bf16(a, bw, nf[n], 0, 0, 0);
            }
        }
        __builtin_amdgcn_s_setprio(0);
    }

    // ---- store out[point][channel] = pf + nf ----
#pragma unroll
    for (int n = 0; n < 4; ++n)
#pragma unroll
        for (int r = 0; r < 4; ++r)
            out[(size_t)(g0 + lg*4 + r) * 64 + n*16 + l15] = pf[n][r] + nf[n][r];
}

// ---------------- correctness fallback (only if ws too small; slow, f32) ----------------
__global__ __launch_bounds__(64) void sb_fallback(
        const float* __restrict__ x, const float* __restrict__ verts,
        const float* __restrict__ shape_w, const float* __restrict__ shape_b,
        const float* __restrict__ delta_w, const float* __restrict__ delta_b,
        const float* __restrict__ ph_w, const float* __restrict__ ph_b,
        const float* __restrict__ nh1_w, const float* __restrict__ nh1_b,
        const float* __restrict__ nh2_w, float* __restrict__ out) {
    __shared__ float cp[72];
    __shared__ float hcol[64];
    __shared__ float dl[24];
    int lane = threadIdx.x;
    int g = blockIdx.x;
    int b = g / Nc;
    const float* xb = x + ((size_t)(b * 64 + lane) << 18);
    float vx = verts[g*3], vy = verts[g*3+1], vz = verts[g*3+2];
    cp[lane] = sample_cm(xb, vx, vy, vz);
    if (lane < 8) {
        float v = 0.0f;
        if      (lane == 0) v = vx;
        else if (lane == 1) v = vy;
        else if (lane == 2) v = vz;
        else if (lane < 7) {
            int i = lane - 3;
            v = 64.0f*(shape_w[i*4]+shape_w[i*4+1]+shape_w[i*4+2]+shape_w[i*4+3]) + shape_b[i];
        }
        cp[64 + lane] = v;
    }
    __syncthreads();
    float pfv = ph_b[lane];
    for (int j = 0; j < 67; ++j) pfv += ph_w[lane*67 + j] * cp[j];
    if (lane < 24) {
        float s = delta_b[lane];
        for (int j = 0; j < 71; ++j) s += delta_w[lane*71 + j] * cp[j];
        dl[lane] = s;
    }
    float h = nh1_b[lane];
    for (int j = 0; j < 67; ++j) h += nh1_w[lane*67 + j] * cp[j];
    hcol[lane] = gelu_exact(h);
    __syncthreads();
    float nfv = 0.0f;
    for (int c2 = 0; c2 < 64; ++c2) nfv += nh2_w[(lane*64 + c2)*9] * hcol[c2];
    for (int k = 0; k < 8; ++k) {
        __syncthreads();
        float nx = vx + dl[3*k], ny = vy + dl[3*k+1], nz = vz + dl[3*k+2];
        cp[lane] = sample_cm(xb, nx, ny, nz);
        if (lane < 3) cp[64 + lane] = (lane == 0) ? nx : (lane == 1) ? ny : nz;
        __syncthreads();
        float hv = nh1_b[lane];
        for (int j = 0; j < 67; ++j) hv += nh1_w[lane*67 + j] * cp[j];
        hcol[lane] = gelu_exact(hv);
        __syncthreads();
        for (int c2 = 0; c2 < 64; ++c2) nfv += nh2_w[(lane*64 + c2)*9 + k + 1] * hcol[c2];
    }
    out[(size_t)g * 64 + lane] = pfv + nfv;
}

// ---------------- launch ----------------
extern "C" void kernel_launch(void* const* d_in, const int* in_sizes, int n_in,
                              void* d_out, int out_size, void* d_ws, size_t ws_size,
                              hipStream_t stream) {
    const float* x       = (const float*)d_in[0];
    const float* verts   = (const float*)d_in[1];
    const float* shape_w = (const float*)d_in[2];
    const float* shape_b = (const float*)d_in[3];
    const float* delta_w = (const float*)d_in[4];
    const float* delta_b = (const float*)d_in[5];
    const float* ph_w    = (const float*)d_in[6];
    const float* ph_b    = (const float*)d_in[7];
    const float* nh1_w   = (const float*)d_in[8];
    const float* nh1_b   = (const float*)d_in[9];
    const float* nh2_w   = (const float*)d_in[10];
    float* out = (float*)d_out;
    char*  wsb = (char*)d_ws;

    const size_t need = XT_BYTE + XT_USHORTS * 2;   // identical to rounds 3-8 (passed)
    if (ws_size >= need) {
        ushort* xt = (ushort*)(wsb + XT_BYTE);
        sb_pack<<<96, 256, 0, stream>>>(shape_w, shape_b, delta_w, delta_b,
                                        ph_w, ph_b, nh1_w, nh1_b, nh2_w, wsb);
        sb_transpose<<<Bc * 4096, 256, 0, stream>>>(x, xt);
        sb_main_mfma<<<NBLK, 64 * WPB, 0, stream>>>(xt, verts, wsb, out);
    } else {
        sb_fallback<<<Bc * Nc, 64, 0, stream>>>(x, verts, shape_w, shape_b, delta_w, delta_b,
                                                ph_w, ph_b, nh1_w, nh1_b, nh2_w, out);
    }
}

// Round 10
// 472.375 us; speedup vs baseline: 1.6582x; 1.6582x over previous
//
#include <hip/hip_runtime.h>
#include <math.h>

// ---------------- problem constants ----------------
constexpr int Bc = 2, Cc = 64, Nc = 50000, Kc = 8;
constexpr int PT = 16;                       // points per wave (MFMA M dim)
constexpr int NBLK = (Bc * Nc) / PT;         // 6250, exact (3125 per batch)

// ---------------- ws byte layout (same as round 8) ----------------
constexpr int BIAS_PH = 16;                  // f32[64]
constexpr int BIAS_N1 = 272;                 // f32[64]
constexpr int BIAS_DL = 528;                 // f32[32] (sv folded, padded)
constexpr int B_PH  = 1024;                  // 12 frags * 1KB
constexpr int B_N1  = 13312;                 // 12 frags
constexpr int B_DH  = 25600;                 // 6 frags (delta hi)
constexpr int B_DLO = 31744;                 // 6 frags (delta lo)
constexpr int B_N2  = 37888;                 // 72 frags -> ends 111616
constexpr size_t XT_BYTE = 262144;           // bf16 volume starts here
constexpr size_t XT_USHORTS = (size_t)Bc * 64 * 64 * 64 * 64;

using bf16x8 = __attribute__((ext_vector_type(8))) short;
using f32x4  = __attribute__((ext_vector_type(4))) float;

// ---------------- helpers ----------------
__device__ __forceinline__ float gelu_exact(float v) {
    return 0.5f * v * (1.0f + erff(v * 0.70710678118654752f));
}
__device__ __forceinline__ ushort f2bf(float f) {           // RNE f32 -> bf16 bits
    unsigned u = __float_as_uint(f);
    unsigned r = (u + 0x7FFFu + ((u >> 16) & 1u)) >> 16;
    return (ushort)r;
}
__device__ __forceinline__ float bf2f(ushort u) {
    return __uint_as_float(((unsigned)u) << 16);
}

// async global->LDS: per-lane global dword, wave-uniform LDS dest (+lane*4 by HW)
__device__ __forceinline__ void gll_dword(const ushort* g, ushort* l) {
    __builtin_amdgcn_global_load_lds(
        (const __attribute__((address_space(1))) unsigned*)(g),
        (__attribute__((address_space(3))) unsigned*)(l), 4, 0, 0);
}

// issue the 8 trilinear corners of one point as 4 corner-pair loads into raw LDS.
// raw chunk layout per pair q: [x0: ch0..63][x1: ch0..63] (128 ushorts).
// pairs: q0=(z0,y0) q1=(z0,y1) q2=(z1,y0) q3=(z1,y1).
__device__ __forceinline__ void issue_point(const ushort* __restrict__ xtb,
                                            ushort* rawp, float* frp, int lane,
                                            float nx, float ny, float nz) {
    float ix = fminf(fmaxf((nx + 1.0f) * 31.5f, 0.0f), 63.0f);
    float iy = fminf(fmaxf((ny + 1.0f) * 31.5f, 0.0f), 63.0f);
    float iz = fminf(fmaxf((nz + 1.0f) * 31.5f, 0.0f), 63.0f);
    float fx0 = floorf(ix), fy0 = floorf(iy), fz0 = floorf(iz);
    int x0 = (int)fx0, y0 = (int)fy0, z0 = (int)fz0;
    int x1 = x0 + (x0 < 63), y1 = y0 + (y0 < 63), z1 = z0 + (z0 < 63);
    if (lane == 0) {                      // stash coords+fracs for combine phase
        frp[0] = nx; frp[1] = ny; frp[2] = nz;
        frp[4] = ix - fx0; frp[5] = iy - fy0; frp[6] = iz - fz0;
    }
    int xs  = (lane < 32) ? x0 : x1;      // lane halves take the two x-lines
    int chp = (lane & 31) << 1;           // channel pair (2 bf16 per dword)
    const ushort* g00 = xtb + ((((z0 << 12) + (y0 << 6) + xs) << 6) + chp);
    const ushort* g01 = xtb + ((((z0 << 12) + (y1 << 6) + xs) << 6) + chp);
    const ushort* g10 = xtb + ((((z1 << 12) + (y0 << 6) + xs) << 6) + chp);
    const ushort* g11 = xtb + ((((z1 << 12) + (y1 << 6) + xs) << 6) + chp);
    gll_dword(g00, rawp + 0);
    gll_dword(g01, rawp + 128);
    gll_dword(g10, rawp + 256);
    gll_dword(g11, rawp + 384);
}

// trilinear combine from raw corner staging; lane = channel
__device__ __forceinline__ float combine_point(const ushort* rawp, int lane,
                                               float fx, float fy, float fz) {
    float v000 = bf2f(rawp[  0 + lane]), v001 = bf2f(rawp[ 64 + lane]);
    float v010 = bf2f(rawp[128 + lane]), v011 = bf2f(rawp[192 + lane]);
    float v100 = bf2f(rawp[256 + lane]), v101 = bf2f(rawp[320 + lane]);
    float v110 = bf2f(rawp[384 + lane]), v111 = bf2f(rawp[448 + lane]);
    float c00 = fmaf(fx, v001 - v000, v000);
    float c01 = fmaf(fx, v011 - v010, v010);
    float c10 = fmaf(fx, v101 - v100, v100);
    float c11 = fmaf(fx, v111 - v110, v110);
    float c0  = fmaf(fy, c01 - c00, c00);
    float c1  = fmaf(fy, c11 - c10, c10);
    return fmaf(fz, c1 - c0, c0);
}

// ---- fallback (channel-major f32) sampling ----
__device__ __forceinline__ float sample_cm(const float* __restrict__ xb,
                                           float gx, float gy, float gz) {
    float ix = fminf(fmaxf((gx + 1.0f) * 31.5f, 0.0f), 63.0f);
    float iy = fminf(fmaxf((gy + 1.0f) * 31.5f, 0.0f), 63.0f);
    float iz = fminf(fmaxf((gz + 1.0f) * 31.5f, 0.0f), 63.0f);
    float fx0 = floorf(ix), fy0 = floorf(iy), fz0 = floorf(iz);
    int x0 = (int)fx0, y0 = (int)fy0, z0 = (int)fz0;
    float fx = ix - fx0, fy = iy - fy0, fz = iz - fz0;
    int x1 = (x0 < 63) ? x0 + 1 : 63;
    int dy = (y0 < 63) ? 64 : 0;
    int dz = (z0 < 63) ? 4096 : 0;
    const float* r = xb + ((z0 << 12) + (y0 << 6));
    float v000 = r[x0],           v001 = r[x1];
    float v010 = r[x0 + dy],      v011 = r[x1 + dy];
    float v100 = r[x0 + dz],      v101 = r[x1 + dz];
    float v110 = r[x0 + dy + dz], v111 = r[x1 + dy + dz];
    float c00 = fmaf(fx, v001 - v000, v000);
    float c01 = fmaf(fx, v011 - v010, v010);
    float c10 = fmaf(fx, v101 - v100, v100);
    float c11 = fmaf(fx, v111 - v110, v110);
    float c0  = fmaf(fy, c01 - c00, c00);
    float c1  = fmaf(fy, c11 - c10, c10);
    return fmaf(fz, c1 - c0, c0);
}

// ---------------- weight packing: B-fragment lane order, bf16 (unchanged) ----------------
__global__ void sb_pack(const float* __restrict__ shape_w, const float* __restrict__ shape_b,
                        const float* __restrict__ delta_w, const float* __restrict__ delta_b,
                        const float* __restrict__ ph_w, const float* __restrict__ ph_b,
                        const float* __restrict__ nh1_w, const float* __restrict__ nh1_b,
                        const float* __restrict__ nh2_w, char* __restrict__ wsb) {
    int tid = blockIdx.x * blockDim.x + threadIdx.x;
    int nt  = gridDim.x * blockDim.x;
    float*  bph = (float*)(wsb + BIAS_PH);
    float*  bn1 = (float*)(wsb + BIAS_N1);
    float*  bdl = (float*)(wsb + BIAS_DL);
    ushort* wph = (ushort*)(wsb + B_PH);
    ushort* wn1 = (ushort*)(wsb + B_N1);
    ushort* wdh = (ushort*)(wsb + B_DH);
    ushort* wdl = (ushort*)(wsb + B_DLO);
    ushort* wn2 = (ushort*)(wsb + B_N2);

    for (int e = tid; e < 64; e += nt) { bph[e] = ph_b[e]; bn1[e] = nh1_b[e]; }
    for (int e = tid; e < 32; e += nt) {
        float v = 0.0f;
        if (e < 24) {
            v = delta_b[e];
#pragma unroll
            for (int i = 0; i < 4; ++i) {   // fold shape_vec (constant) into bias, f32 exact
                float sv = 64.0f * (shape_w[i*4] + shape_w[i*4+1] + shape_w[i*4+2] + shape_w[i*4+3])
                         + shape_b[i];
                v += sv * delta_w[e * 71 + 67 + i];
            }
        }
        bdl[e] = v;
    }
    for (int e = tid; e < 6144; e += nt) {
        int frag = e >> 9, lane = (e >> 3) & 63, j = e & 7;
        int kt = frag >> 2, n = frag & 3;
        int k = kt * 32 + ((lane >> 4) << 3) + j;
        int col = n * 16 + (lane & 15);
        wph[e] = (k < 67) ? f2bf(ph_w[col * 67 + k])  : (ushort)0;
        wn1[e] = (k < 67) ? f2bf(nh1_w[col * 67 + k]) : (ushort)0;
    }
    for (int e = tid; e < 3072; e += nt) {
        int frag = e >> 9, lane = (e >> 3) & 63, j = e & 7;
        int kt = frag >> 1, n = frag & 1;
        int k = kt * 32 + ((lane >> 4) << 3) + j;
        int col = n * 16 + (lane & 15);
        float w = (col < 24 && k < 67) ? delta_w[col * 71 + k] : 0.0f;
        ushort hi = f2bf(w);
        wdh[e] = hi;
        wdl[e] = f2bf(w - bf2f(hi));
    }
    for (int e = tid; e < 36864; e += nt) {
        int frag = e >> 9, lane = (e >> 3) & 63, j = e & 7;
        int c9 = frag >> 3, kt = (frag >> 2) & 1, n = frag & 3;
        int k = kt * 32 + ((lane >> 4) << 3) + j;
        int c = n * 16 + (lane & 15);
        wn2[e] = f2bf(nh2_w[(c * 64 + k) * 9 + c9]);
    }
}

// ---------------- transpose x [B,C,64^3] f32 -> xt [B,64^3,C] bf16 (unchanged) ----------------
__global__ __launch_bounds__(256) void sb_transpose(const float* __restrict__ x,
                                                    ushort* __restrict__ xt) {
    __shared__ float tile[64][65];
    int blk = blockIdx.x;
    int b = blk >> 12, zy = blk & 4095;
    const float* __restrict__ src = x + ((size_t)b << 24) + zy * 64;
    unsigned* __restrict__ dst32 = (unsigned*)(xt + ((size_t)b << 24) + (size_t)zy * 4096);
    int t = threadIdx.x;
    int xx = t & 63, c0 = t >> 6;
#pragma unroll
    for (int i = 0; i < 16; ++i) {
        int c = i * 4 + c0;
        tile[c][xx] = src[((size_t)c << 18) + xx];
    }
    __syncthreads();
    int cp = t & 31, xs0 = t >> 5;
#pragma unroll
    for (int i = 0; i < 8; ++i) {
        int xs = i * 8 + xs0;
        unsigned lo = f2bf(tile[cp * 2][xs]);
        unsigned hi = f2bf(tile[cp * 2 + 1][xs]);
        dst32[xs * 32 + cp] = lo | (hi << 16);
    }
}

// ---------------- main MFMA kernel: 1 wave = 16 points, async corner pipeline ----------------
__global__ __launch_bounds__(64) void sb_main_mfma(
        const ushort* __restrict__ xt, const float* __restrict__ verts,
        const char* __restrict__ wsb, float* __restrict__ out) {
    __shared__ __align__(16) ushort stage[PT * 104];  // A tile [point][K..95], pad stride 104
    __shared__ __align__(16) ushort hst[PT * 72];     // gelu(h) A tile
    __shared__ __align__(16) ushort raw[PT * 512];    // async corner staging (16 KB)
    __shared__ float cst[PT * 4];                     // vertex coords
    __shared__ float dls[PT * 32];                    // delta outputs
    __shared__ float fr[PT * 8];                      // per-point {nx,ny,nz,_,fx,fy,fz,_}

    const int lane = threadIdx.x;
    const int l15 = lane & 15, lg = lane >> 4;
    const int g0 = blockIdx.x * PT;
    const ushort* __restrict__ xtb = xt + ((size_t)(g0 / Nc) << 24);

    const float*  bph = (const float*)(wsb + BIAS_PH);
    const float*  bn1 = (const float*)(wsb + BIAS_N1);
    const float*  bdl = (const float*)(wsb + BIAS_DL);
    const ushort* Wph = (const ushort*)(wsb + B_PH);
    const ushort* Wn1 = (const ushort*)(wsb + B_N1);
    const ushort* Wdh = (const ushort*)(wsb + B_DH);
    const ushort* Wdl = (const ushort*)(wsb + B_DLO);
    const ushort* Wn2 = (const ushort*)(wsb + B_N2);

    // zero-init A tile (pad cols 72..103 are MFMA-read vs zero weights; NaN*0=NaN otherwise)
#pragma unroll
    for (int i = 0; i < (PT * 104) / 64; ++i) stage[i * 64 + lane] = 0;

    float bias_p[4], bias_h[4], bias_d[2];
#pragma unroll
    for (int n = 0; n < 4; ++n) { bias_p[n] = bph[n*16 + l15]; bias_h[n] = bn1[n*16 + l15]; }
#pragma unroll
    for (int n = 0; n < 2; ++n) bias_d[n] = bdl[n*16 + l15];

    if (lane < PT) {
        const float* vp = verts + (size_t)(g0 + lane) * 3;
        cst[lane*4+0] = vp[0]; cst[lane*4+1] = vp[1]; cst[lane*4+2] = vp[2];
    }
    __syncthreads();

    // ---- issue column 0 corner loads (async) ----
#pragma unroll 4
    for (int p = 0; p < PT; ++p)
        issue_point(xtb, raw + p * 512, fr + p * 8, lane,
                    cst[p*4+0], cst[p*4+1], cst[p*4+2]);
    __syncthreads();                 // vmcnt(0): col-0 corners landed in raw

    // ---- combine column 0 -> stage ----
#pragma unroll 4
    for (int p = 0; p < PT; ++p)
        stage[p * 104 + lane] = f2bf(combine_point(raw + p * 512, lane,
                                     fr[p*8+4], fr[p*8+5], fr[p*8+6]));
    if (lane < PT) {                 // coord block cols 64..71 (67.. zero)
        uint4 cw;
        cw.x = (unsigned)f2bf(fr[lane*8+0]) | ((unsigned)f2bf(fr[lane*8+1]) << 16);
        cw.y = (unsigned)f2bf(fr[lane*8+2]);
        cw.z = 0u; cw.w = 0u;
        *(uint4*)(stage + lane * 104 + 64) = cw;
    }
    __syncthreads();

    // ---- merged GEMM pass: ph + nh1(col0) + delta(hi+lo), K=96 ----
    f32x4 pf[4], nf[4], hh[4], dd[2];
#pragma unroll
    for (int n = 0; n < 4; ++n) {
        pf[n] = (f32x4){bias_p[n], bias_p[n], bias_p[n], bias_p[n]};
        hh[n] = (f32x4){bias_h[n], bias_h[n], bias_h[n], bias_h[n]};
        nf[n] = (f32x4){0.f, 0.f, 0.f, 0.f};
    }
#pragma unroll
    for (int n = 0; n < 2; ++n) dd[n] = (f32x4){bias_d[n], bias_d[n], bias_d[n], bias_d[n]};

    __builtin_amdgcn_s_setprio(1);
#pragma unroll
    for (int kt = 0; kt < 3; ++kt) {
        bf16x8 a = *(const bf16x8*)(stage + l15 * 104 + kt * 32 + lg * 8);
#pragma unroll
        for (int n = 0; n < 4; ++n) {
            bf16x8 bw = *(const bf16x8*)(Wph + ((kt*4 + n) << 9) + lane * 8);
            pf[n] = __builtin_amdgcn_mfma_f32_16x16x32_bf16(a, bw, pf[n], 0, 0, 0);
            bf16x8 b1 = *(const bf16x8*)(Wn1 + ((kt*4 + n) << 9) + lane * 8);
            hh[n] = __builtin_amdgcn_mfma_f32_16x16x32_bf16(a, b1, hh[n], 0, 0, 0);
        }
#pragma unroll
        for (int n = 0; n < 2; ++n) {
            bf16x8 bh = *(const bf16x8*)(Wdh + ((kt*2 + n) << 9) + lane * 8);
            dd[n] = __builtin_amdgcn_mfma_f32_16x16x32_bf16(a, bh, dd[n], 0, 0, 0);
            bf16x8 bl = *(const bf16x8*)(Wdl + ((kt*2 + n) << 9) + lane * 8);
            dd[n] = __builtin_amdgcn_mfma_f32_16x16x32_bf16(a, bl, dd[n], 0, 0, 0);
        }
    }
    __builtin_amdgcn_s_setprio(0);

    // D layout: row=(lg*4+r) [point], col=n*16+l15
#pragma unroll
    for (int n = 0; n < 2; ++n)
#pragma unroll
        for (int r = 0; r < 4; ++r)
            dls[(lg*4 + r) * 32 + n*16 + l15] = dd[n][r];

    // ---- issue column 1 (neighbour j=0) early: hides under gelu + nh2 col0 ----
#pragma unroll 4
    for (int p = 0; p < PT; ++p) {
        float nx = cst[p*4+0] + dls[p*32 + 0];
        float ny = cst[p*4+1] + dls[p*32 + 1];
        float nz = cst[p*4+2] + dls[p*32 + 2];
        issue_point(xtb, raw + p * 512, fr + p * 8, lane, nx, ny, nz);
    }

    // gelu(col0 h) -> hst
#pragma unroll
    for (int n = 0; n < 4; ++n)
#pragma unroll
        for (int r = 0; r < 4; ++r)
            hst[(lg*4 + r) * 72 + n*16 + l15] = f2bf(gelu_exact(hh[n][r]));

    // nh2 column 0
    __builtin_amdgcn_s_setprio(1);
#pragma unroll
    for (int kt = 0; kt < 2; ++kt) {
        bf16x8 a = *(const bf16x8*)(hst + l15 * 72 + kt * 32 + lg * 8);
#pragma unroll
        for (int n = 0; n < 4; ++n) {
            bf16x8 bw = *(const bf16x8*)(Wn2 + ((kt*4 + n) << 9) + lane * 8);
            nf[n] = __builtin_amdgcn_mfma_f32_16x16x32_bf16(a, bw, nf[n], 0, 0, 0);
        }
    }
    __builtin_amdgcn_s_setprio(0);

    // ---- columns 1..8 (pipelined: combine k, issue k+1, GEMM k) ----
    for (int k = 1; k <= Kc; ++k) {
        __syncthreads();             // vmcnt(0): col-k corners landed

        // combine col k -> stage
#pragma unroll 4
        for (int p = 0; p < PT; ++p)
            stage[p * 104 + lane] = f2bf(combine_point(raw + p * 512, lane,
                                         fr[p*8+4], fr[p*8+5], fr[p*8+6]));
        if (lane < PT) {
            uint4 cw;
            cw.x = (unsigned)f2bf(fr[lane*8+0]) | ((unsigned)f2bf(fr[lane*8+1]) << 16);
            cw.y = (unsigned)f2bf(fr[lane*8+2]);
            cw.z = 0u; cw.w = 0u;
            *(uint4*)(stage + lane * 104 + 64) = cw;
        }

        // issue col k+1 (reads of raw/fr above precede these writes in LDS pipe order;
        // gll writeback arrives >= memory latency after issue — no WAR in practice)
        if (k < Kc) {
#pragma unroll 4
            for (int p = 0; p < PT; ++p) {
                float nx = cst[p*4+0] + dls[p*32 + 3*k + 0];
                float ny = cst[p*4+1] + dls[p*32 + 3*k + 1];
                float nz = cst[p*4+2] + dls[p*32 + 3*k + 2];
                issue_point(xtb, raw + p * 512, fr + p * 8, lane, nx, ny, nz);
            }
        }

        // nh1 GEMM on stage
        f32x4 hk[4];
#pragma unroll
        for (int n = 0; n < 4; ++n) hk[n] = (f32x4){bias_h[n], bias_h[n], bias_h[n], bias_h[n]};
        __builtin_amdgcn_s_setprio(1);
#pragma unroll
        for (int kt = 0; kt < 3; ++kt) {
            bf16x8 a = *(const bf16x8*)(stage + l15 * 104 + kt * 32 + lg * 8);
#pragma unroll
            for (int n = 0; n < 4; ++n) {
                bf16x8 b1 = *(const bf16x8*)(Wn1 + ((kt*4 + n) << 9) + lane * 8);
                hk[n] = __builtin_amdgcn_mfma_f32_16x16x32_bf16(a, b1, hk[n], 0, 0, 0);
            }
        }
        __builtin_amdgcn_s_setprio(0);

        // gelu -> hst
#pragma unroll
        for (int n = 0; n < 4; ++n)
#pragma unroll
            for (int r = 0; r < 4; ++r)
                hst[(lg*4 + r) * 72 + n*16 + l15] = f2bf(gelu_exact(hk[n][r]));

        // nh2 col k
        const ushort* Wk = Wn2 + ((size_t)k << 12);
        __builtin_amdgcn_s_setprio(1);
#pragma unroll
        for (int kt = 0; kt < 2; ++kt) {
            bf16x8 a = *(const bf16x8*)(hst + l15 * 72 + kt * 32 + lg * 8);
#pragma unroll
            for (int n = 0; n < 4; ++n) {
                bf16x8 bw = *(const bf16x8*)(Wk + ((kt*4 + n) << 9) + lane * 8);
                nf[n] = __builtin_amdgcn_mfma_f32_16x16x32_bf16(a, bw, nf[n], 0, 0, 0);
            }
        }
        __builtin_amdgcn_s_setprio(0);
    }

    // ---- store out[point][channel] = pf + nf ----
#pragma unroll
    for (int n = 0; n < 4; ++n)
#pragma unroll
        for (int r = 0; r < 4; ++r)
            out[(size_t)(g0 + lg*4 + r) * 64 + n*16 + l15] = pf[n][r] + nf[n][r];
}

// ---------------- correctness fallback (only if ws too small; slow, f32) ----------------
__global__ __launch_bounds__(64) void sb_fallback(
        const float* __restrict__ x, const float* __restrict__ verts,
        const float* __restrict__ shape_w, const float* __restrict__ shape_b,
        const float* __restrict__ delta_w, const float* __restrict__ delta_b,
        const float* __restrict__ ph_w, const float* __restrict__ ph_b,
        const float* __restrict__ nh1_w, const float* __restrict__ nh1_b,
        const float* __restrict__ nh2_w, float* __restrict__ out) {
    __shared__ float cp[72];
    __shared__ float hcol[64];
    __shared__ float dl[24];
    int lane = threadIdx.x;
    int g = blockIdx.x;
    int b = g / Nc;
    const float* xb = x + ((size_t)(b * 64 + lane) << 18);
    float vx = verts[g*3], vy = verts[g*3+1], vz = verts[g*3+2];
    cp[lane] = sample_cm(xb, vx, vy, vz);
    if (lane < 8) {
        float v = 0.0f;
        if      (lane == 0) v = vx;
        else if (lane == 1) v = vy;
        else if (lane == 2) v = vz;
        else if (lane < 7) {
            int i = lane - 3;
            v = 64.0f*(shape_w[i*4]+shape_w[i*4+1]+shape_w[i*4+2]+shape_w[i*4+3]) + shape_b[i];
        }
        cp[64 + lane] = v;
    }
    __syncthreads();
    float pfv = ph_b[lane];
    for (int j = 0; j < 67; ++j) pfv += ph_w[lane*67 + j] * cp[j];
    if (lane < 24) {
        float s = delta_b[lane];
        for (int j = 0; j < 71; ++j) s += delta_w[lane*71 + j] * cp[j];
        dl[lane] = s;
    }
    float h = nh1_b[lane];
    for (int j = 0; j < 67; ++j) h += nh1_w[lane*67 + j] * cp[j];
    hcol[lane] = gelu_exact(h);
    __syncthreads();
    float nfv = 0.0f;
    for (int c2 = 0; c2 < 64; ++c2) nfv += nh2_w[(lane*64 + c2)*9] * hcol[c2];
    for (int k = 0; k < 8; ++k) {
        __syncthreads();
        float nx = vx + dl[3*k], ny = vy + dl[3*k+1], nz = vz + dl[3*k+2];
        cp[lane] = sample_cm(xb, nx, ny, nz);
        if (lane < 3) cp[64 + lane] = (lane == 0) ? nx : (lane == 1) ? ny : nz;
        __syncthreads();
        float hv = nh1_b[lane];
        for (int j = 0; j < 67; ++j) hv += nh1_w[lane*67 + j] * cp[j];
        hcol[lane] = gelu_exact(hv);
        __syncthreads();
        for (int c2 = 0; c2 < 64; ++c2) nfv += nh2_w[(lane*64 + c2)*9 + k + 1] * hcol[c2];
    }
    out[(size_t)g * 64 + lane] = pfv + nfv;
}

// ---------------- launch ----------------
extern "C" void kernel_launch(void* const* d_in, const int* in_sizes, int n_in,
                              void* d_out, int out_size, void* d_ws, size_t ws_size,
                              hipStream_t stream) {
    const float* x       = (const float*)d_in[0];
    const float* verts   = (const float*)d_in[1];
    const float* shape_w = (const float*)d_in[2];
    const float* shape_b = (const float*)d_in[3];
    const float* delta_w = (const float*)d_in[4];
    const float* delta_b = (const float*)d_in[5];
    const float* ph_w    = (const float*)d_in[6];
    const float* ph_b    = (const float*)d_in[7];
    const float* nh1_w   = (const float*)d_in[8];
    const float* nh1_b   = (const float*)d_in[9];
    const float* nh2_w   = (const float*)d_in[10];
    float* out = (float*)d_out;
    char*  wsb = (char*)d_ws;

    const size_t need = XT_BYTE + XT_USHORTS * 2;   // identical to rounds 3-9 (passed)
    if (ws_size >= need) {
        ushort* xt = (ushort*)(wsb + XT_BYTE);
        sb_pack<<<96, 256, 0, stream>>>(shape_w, shape_b, delta_w, delta_b,
                                        ph_w, ph_b, nh1_w, nh1_b, nh2_w, wsb);
        sb_transpose<<<Bc * 4096, 256, 0, stream>>>(x, xt);
        sb_main_mfma<<<NBLK, 64, 0, stream>>>(xt, verts, wsb, out);
    } else {
        sb_fallback<<<Bc * Nc, 64, 0, stream>>>(x, verts, shape_w, shape_b, delta_w, delta_b,
                                                ph_w, ph_b, nh1_w, nh1_b, nh2_w, out);
    }
}